// Round 8
// baseline (116.488 us; speedup 1.0000x reference)
//
#include <hip/hip_runtime.h>
#include <hip/hip_bf16.h>

#define NROWS 8192
#define DIM   128
#define NT    64                  // NROWS / 128 tiles per dim
#define NBLK  (NT * (NT + 1) / 2) // 2080 triangle tiles
#define REP   3                   // diagnostic: 3x identical work -> pdist tops rocprof table
#define TOTAL_OUT 33550336u       // NROWS*(NROWS-1)/2

typedef short bf16x8 __attribute__((ext_vector_type(8)));
typedef float f32x4  __attribute__((ext_vector_type(4)));
typedef unsigned short u16x8 __attribute__((ext_vector_type(8)));

// fp32 -> bf16 round-to-nearest-even
static __device__ inline unsigned short f32_to_bf16(float f) {
    unsigned int u = __float_as_uint(f);
    u += 0x7FFFu + ((u >> 16) & 1u);
    return (unsigned short)(u >> 16);
}

// Block = one 16-row group. bf16 convert + FRAGMENT-MAJOR layout:
//   Xr[((g*4 + kk)*64 + lane)*8] : row g*16+(lane&15), cols ((kk*4+(lane>>4))*8 ..+8)
// Each MFMA fragment load in pdist = one contiguous 1KB wave load. Also fp32 norms.
__global__ __launch_bounds__(256) void prep_kernel(const float* __restrict__ X,
                                                   unsigned short* __restrict__ Xr,
                                                   float* __restrict__ sq,
                                                   float* __restrict__ out) {
    __shared__ float sm[16][17];
    const int g = blockIdx.x;
    const int t = threadIdx.x;
    const int kk = t >> 6, lane = t & 63;
    const int lrow = lane & 15, kgrp = lane >> 4;

    const float* src = X + (size_t)(g * 16 + lrow) * DIM + (kk * 4 + kgrp) * 8;
    const float4 v0 = *reinterpret_cast<const float4*>(src);
    const float4 v1 = *reinterpret_cast<const float4*>(src + 4);

    u16x8 h;
    h[0] = f32_to_bf16(v0.x); h[1] = f32_to_bf16(v0.y);
    h[2] = f32_to_bf16(v0.z); h[3] = f32_to_bf16(v0.w);
    h[4] = f32_to_bf16(v1.x); h[5] = f32_to_bf16(v1.y);
    h[6] = f32_to_bf16(v1.z); h[7] = f32_to_bf16(v1.w);
    *reinterpret_cast<u16x8*>(Xr + ((size_t)(g * 4 + kk) * 64 + lane) * 8) = h;

    float p = v0.x * v0.x + v0.y * v0.y + v0.z * v0.z + v0.w * v0.w
            + v1.x * v1.x + v1.y * v1.y + v1.z * v1.z + v1.w * v1.w;
    sm[lrow][kk * 4 + kgrp] = p;
    __syncthreads();
    if (t < 16) {
        float s = 0.f;
        #pragma unroll
        for (int j = 0; j < 16; ++j) s += sm[t][j];
        sq[g * 16 + t] = s;
    }
    if (g == 0 && t == 0) out[TOTAL_OUT - 1] = 0.0f; // skipped pair (0,1) slot
}

// R3-identical compute + scatter store, replicated REP times in one dispatch
// (blocks >= NBLK redo identical work -> identical values -> benign).
// Purpose: a single ~150us dispatch whose rocprof counters (FETCH/WRITE/
// MfmaUtil/Occupancy) are finally visible above the harness fill kernels.
__global__ __launch_bounds__(256, 4) void pdist_kernel(const unsigned short* __restrict__ Xr,
                                                       const float* __restrict__ sq,
                                                       float* __restrict__ out) {
    const int t = threadIdx.x;
    int bt = blockIdx.x;
    while (bt >= NBLK) bt -= NBLK;
    // decode triangle index: bt = bj*(bj+1)/2 + bi, bi <= bj
    int bj = (int)((sqrtf(8.0f * (float)bt + 1.0f) - 1.0f) * 0.5f);
    while ((bj + 1) * (bj + 2) / 2 <= bt) ++bj;
    while (bj * (bj + 1) / 2 > bt) --bj;
    const int bi = bt - bj * (bj + 1) / 2;

    const int wid  = t >> 6;
    const int lane = t & 63;
    const int wr   = wid >> 1;   // wave row (l dim), 0..1
    const int wc   = wid & 1;    // wave col (u dim), 0..1
    const int lrow = lane & 15;
    const int kgrp = lane >> 4;

    const bf16x8* __restrict__ F = reinterpret_cast<const bf16x8*>(Xr);
    const int gA = bi * 8 + wr * 4;
    const int gB = bj * 8 + wc * 4;

    f32x4 acc[4][4];
    const f32x4 fzero = {0.f, 0.f, 0.f, 0.f};
    #pragma unroll
    for (int m = 0; m < 4; ++m)
        #pragma unroll
        for (int n = 0; n < 4; ++n) acc[m][n] = fzero;

    bf16x8 a[2][4], b[2][4];
    #pragma unroll
    for (int m = 0; m < 4; ++m) {
        a[0][m] = F[((gA + m) * 4 + 0) * 64 + lane];
        b[0][m] = F[((gB + m) * 4 + 0) * 64 + lane];
    }
    #pragma unroll
    for (int kk = 0; kk < 4; ++kk) {
        const int cur = kk & 1, nxt = cur ^ 1;
        if (kk < 3) {
            #pragma unroll
            for (int m = 0; m < 4; ++m) {
                a[nxt][m] = F[((gA + m) * 4 + kk + 1) * 64 + lane];
                b[nxt][m] = F[((gB + m) * 4 + kk + 1) * 64 + lane];
            }
        }
        #pragma unroll
        for (int m = 0; m < 4; ++m)
            #pragma unroll
            for (int n = 0; n < 4; ++n)
                acc[m][n] = __builtin_amdgcn_mfma_f32_16x16x32_bf16(a[cur][m], b[cur][n], acc[m][n], 0, 0, 0);
    }

    const int l0 = bi * 128 + wr * 64;
    const int u0 = bj * 128 + wc * 64;
    const int rj = kgrp * 4;

    float squ[4];
    f32x4 sql[4];
    #pragma unroll
    for (int n = 0; n < 4; ++n) squ[n] = sq[u0 + n * 16 + lrow];
    #pragma unroll
    for (int m = 0; m < 4; ++m)
        sql[m] = *reinterpret_cast<const f32x4*>(sq + l0 + m * 16 + rj);

    if (bi != bj) {
        #pragma unroll
        for (int m = 0; m < 4; ++m) {
            #pragma unroll
            for (int n = 0; n < 4; ++n) {
                const int u = u0 + n * 16 + lrow;
                const size_t base = ((size_t)u * (u - 1)) / 2 - 1 + (size_t)(l0 + m * 16 + rj);
                f32x4 d;
                #pragma unroll
                for (int j = 0; j < 4; ++j) d[j] = sql[m][j] + squ[n] - 2.0f * acc[m][n][j];
                __builtin_memcpy(out + base, &d, 16);
            }
        }
    } else {
        // diagonal tile: mask l < u && u >= 2
        #pragma unroll
        for (int m = 0; m < 4; ++m) {
            #pragma unroll
            for (int n = 0; n < 4; ++n) {
                const int u = u0 + n * 16 + lrow;
                #pragma unroll
                for (int j = 0; j < 4; ++j) {
                    const int l = l0 + m * 16 + rj + j;
                    if (l < u && u >= 2) {
                        out[((size_t)u * (u - 1)) / 2 - 1 + l] = sql[m][j] + squ[n] - 2.0f * acc[m][n][j];
                    }
                }
            }
        }
    }
}

extern "C" void kernel_launch(void* const* d_in, const int* in_sizes, int n_in,
                              void* d_out, int out_size, void* d_ws, size_t ws_size,
                              hipStream_t stream) {
    const float* X = (const float*)d_in[0];
    float* out = (float*)d_out;
    unsigned short* Xr = (unsigned short*)d_ws;                       // 2 MB bf16, fragment-major
    float* sq = (float*)((char*)d_ws + (size_t)NROWS * DIM * 2);      // 32 KB norms

    prep_kernel<<<NROWS / 16, 256, 0, stream>>>(X, Xr, sq, out);
    pdist_kernel<<<NBLK * REP, 256, 0, stream>>>(Xr, sq, out);
}

// Round 9
// 84.728 us; speedup vs baseline: 1.3748x; 1.3748x over previous
//
#include <hip/hip_runtime.h>
#include <hip/hip_bf16.h>

#define NROWS 8192
#define DIM   128
#define TOTAL_OUT 33550336u       // NROWS*(NROWS-1)/2
#define CHUNK 4                   // l-tiles per block -> 2KB per-u-row runs
#define NBLK_P 1088               // sum over uj=0..127 of ceil(((uj>>1)+1)/CHUNK)

typedef short bf16x8 __attribute__((ext_vector_type(8)));
typedef float f32x4  __attribute__((ext_vector_type(4)));
typedef unsigned short u16x8 __attribute__((ext_vector_type(8)));

// fp32 -> bf16 round-to-nearest-even
static __device__ inline unsigned short f32_to_bf16(float f) {
    unsigned int u = __float_as_uint(f);
    u += 0x7FFFu + ((u >> 16) & 1u);
    return (unsigned short)(u >> 16);
}

// S4(a) = sum_{i=1..a} ceil(i/4)
static __device__ inline int S4(int a) { int q = a >> 2, r = a & 3; return 2 * q * (q + 1) + r * (q + 1); }
// cumulative block count before u-tile uj (64-row u-tiles, ext(uj)=(uj>>1)+1 l-tiles)
static __device__ inline int cumf(int uj) { int a = uj >> 1, b = uj & 1; return 2 * S4(a) + b * ((a >> 2) + 1); }

// Block = one 16-row group. bf16 convert + FRAGMENT-MAJOR layout:
//   Xr[((g*4 + kk)*64 + lane)*8] : row g*16+(lane&15), cols ((kk*4+(lane>>4))*8 ..+8)
// Each MFMA fragment load in pdist = one contiguous 1KB wave load. Also fp32 norms.
__global__ __launch_bounds__(256) void prep_kernel(const float* __restrict__ X,
                                                   unsigned short* __restrict__ Xr,
                                                   float* __restrict__ sq,
                                                   float* __restrict__ out) {
    __shared__ float sm[16][17];
    const int g = blockIdx.x;
    const int t = threadIdx.x;
    const int kk = t >> 6, lane = t & 63;
    const int lrow = lane & 15, kgrp = lane >> 4;

    const float* src = X + (size_t)(g * 16 + lrow) * DIM + (kk * 4 + kgrp) * 8;
    const float4 v0 = *reinterpret_cast<const float4*>(src);
    const float4 v1 = *reinterpret_cast<const float4*>(src + 4);

    u16x8 h;
    h[0] = f32_to_bf16(v0.x); h[1] = f32_to_bf16(v0.y);
    h[2] = f32_to_bf16(v0.z); h[3] = f32_to_bf16(v0.w);
    h[4] = f32_to_bf16(v1.x); h[5] = f32_to_bf16(v1.y);
    h[6] = f32_to_bf16(v1.z); h[7] = f32_to_bf16(v1.w);
    *reinterpret_cast<u16x8*>(Xr + ((size_t)(g * 4 + kk) * 64 + lane) * 8) = h;

    float p = v0.x * v0.x + v0.y * v0.y + v0.z * v0.z + v0.w * v0.w
            + v1.x * v1.x + v1.y * v1.y + v1.z * v1.z + v1.w * v1.w;
    sm[lrow][kk * 4 + kgrp] = p;
    __syncthreads();
    if (t < 16) {
        float s = 0.f;
        #pragma unroll
        for (int j = 0; j < 16; ++j) s += sm[t][j];
        sq[g * 16 + t] = s;
    }
    if (g == 0 && t == 0) out[TOTAL_OUT - 1] = 0.0f; // skipped pair (0,1) slot
}

// Block = 64 u-rows (tile uj, half per wave pair) x up to 512 l (CHUNK l-tiles).
// u-side B fragments register-resident; inner loop walks l-tiles so each u-row's
// output span grows to 2KB sequential (L2-merged) -> DRAM page locality.
// Dispatch largest-uj first (blockIdx reversed). No staging LDS; frag-major L2 loads.
__global__ __launch_bounds__(256, 2) void pdist_kernel(const unsigned short* __restrict__ Xr,
                                                       const float* __restrict__ sq,
                                                       float* __restrict__ out) {
    const int t   = threadIdx.x;
    const int rid = NBLK_P - 1 - (int)blockIdx.x;    // descending uj dispatch
    int lo = 0, hi = 127;
    while (lo < hi) { int mid = (lo + hi + 1) >> 1; if (cumf(mid) <= rid) lo = mid; else hi = mid - 1; }
    const int uj    = lo;
    const int chunk = rid - cumf(uj);
    const int ext   = (uj >> 1) + 1;                 // l-tiles needed for this u-tile
    const int t0    = chunk * CHUNK;
    const int t1    = (t0 + CHUNK < ext) ? (t0 + CHUNK) : ext;

    const int wid  = t >> 6;
    const int lane = t & 63;
    const int wr   = wid >> 1;    // l half (0..1) within the 128-l tile
    const int wc   = wid & 1;     // u half (0..1) within the 64-u tile
    const int lrow = lane & 15;
    const int kgrp = lane >> 4;

    const bf16x8* __restrict__ F = reinterpret_cast<const bf16x8*>(Xr);

    // resident u-side (B operand): 32 u-rows per wave
    bf16x8 b[2][4];
    #pragma unroll
    for (int n = 0; n < 2; ++n)
        #pragma unroll
        for (int kk = 0; kk < 4; ++kk)
            b[n][kk] = F[(((uj * 4 + wc * 2 + n) * 4) + kk) * 64 + lane];

    const int u0 = uj * 64 + wc * 32;
    float squ[2];
    #pragma unroll
    for (int n = 0; n < 2; ++n) squ[n] = sq[u0 + n * 16 + lrow];

    bf16x8 aA[4][4], aB[4][4];    // double-buffered l-side (A operand)
    auto loadA = [&](bf16x8 (&buf)[4][4], int lt) {
        #pragma unroll
        for (int m = 0; m < 4; ++m)
            #pragma unroll
            for (int kk = 0; kk < 4; ++kk)
                buf[m][kk] = F[((lt * 8 + wr * 4 + m) * 4 + kk) * 64 + lane];
    };

    loadA(aA, t0);
    for (int lt = t0; lt < t1; ++lt) {
        f32x4 acc[4][2];
        #pragma unroll
        for (int m = 0; m < 4; ++m) { acc[m][0] = (f32x4){0.f,0.f,0.f,0.f}; acc[m][1] = (f32x4){0.f,0.f,0.f,0.f}; }

        if (((lt - t0) & 1) == 0) {
            if (lt + 1 < t1) loadA(aB, lt + 1);
            #pragma unroll
            for (int kk = 0; kk < 4; ++kk)
                #pragma unroll
                for (int m = 0; m < 4; ++m) {
                    acc[m][0] = __builtin_amdgcn_mfma_f32_16x16x32_bf16(aA[m][kk], b[0][kk], acc[m][0], 0, 0, 0);
                    acc[m][1] = __builtin_amdgcn_mfma_f32_16x16x32_bf16(aA[m][kk], b[1][kk], acc[m][1], 0, 0, 0);
                }
        } else {
            if (lt + 1 < t1) loadA(aA, lt + 1);
            #pragma unroll
            for (int kk = 0; kk < 4; ++kk)
                #pragma unroll
                for (int m = 0; m < 4; ++m) {
                    acc[m][0] = __builtin_amdgcn_mfma_f32_16x16x32_bf16(aB[m][kk], b[0][kk], acc[m][0], 0, 0, 0);
                    acc[m][1] = __builtin_amdgcn_mfma_f32_16x16x32_bf16(aB[m][kk], b[1][kk], acc[m][1], 0, 0, 0);
                }
        }

        // epilogue for this l-tile: l = lbase + m*16 + kgrp*4 + j, u = u0 + n*16 + lrow
        const int lbase = lt * 128 + wr * 64;
        f32x4 sql[4];
        #pragma unroll
        for (int m = 0; m < 4; ++m)
            sql[m] = *reinterpret_cast<const f32x4*>(sq + lbase + m * 16 + kgrp * 4);

        if (lt * 128 + 128 <= uj * 64) {
            // fully below diagonal: unconditional 16B stores
            #pragma unroll
            for (int m = 0; m < 4; ++m) {
                #pragma unroll
                for (int n = 0; n < 2; ++n) {
                    const int u = u0 + n * 16 + lrow;
                    const size_t base = (size_t)u * (size_t)(u - 1) / 2 - 1
                                      + (size_t)(lbase + m * 16 + kgrp * 4);
                    f32x4 d;
                    #pragma unroll
                    for (int j = 0; j < 4; ++j) d[j] = sql[m][j] + squ[n] - 2.0f * acc[m][n][j];
                    __builtin_memcpy(out + base, &d, 16);
                }
            }
        } else {
            // diagonal-crossing tile: per-element mask l < u (u>=2)
            #pragma unroll
            for (int m = 0; m < 4; ++m) {
                #pragma unroll
                for (int n = 0; n < 2; ++n) {
                    const int u = u0 + n * 16 + lrow;
                    if (u >= 2) {
                        #pragma unroll
                        for (int j = 0; j < 4; ++j) {
                            const int l = lbase + m * 16 + kgrp * 4 + j;
                            if (l < u)
                                out[(size_t)u * (size_t)(u - 1) / 2 - 1 + l] =
                                    sql[m][j] + squ[n] - 2.0f * acc[m][n][j];
                        }
                    }
                }
            }
        }
    }
}

extern "C" void kernel_launch(void* const* d_in, const int* in_sizes, int n_in,
                              void* d_out, int out_size, void* d_ws, size_t ws_size,
                              hipStream_t stream) {
    const float* X = (const float*)d_in[0];
    float* out = (float*)d_out;
    unsigned short* Xr = (unsigned short*)d_ws;                       // 2 MB bf16, fragment-major
    float* sq = (float*)((char*)d_ws + (size_t)NROWS * DIM * 2);      // 32 KB norms

    prep_kernel<<<NROWS / 16, 256, 0, stream>>>(X, Xr, sq, out);
    pdist_kernel<<<NBLK_P, 256, 0, stream>>>(Xr, sq, out);
}